// Round 2
// baseline (146.428 us; speedup 1.0000x reference)
//
#include <hip/hip_runtime.h>
#include <stdint.h>

#define IN_F 4096
#define OUT_F 4096
#define NG 32

typedef __attribute__((ext_vector_type(8))) _Float16 half8;
typedef __attribute__((ext_vector_type(2))) _Float16 half2t;
typedef __attribute__((ext_vector_type(4))) float floatx4;

// ---------------------------------------------------------------------------
// Prep kernel: (a) convert x f32 -> fp16 with k-permuted pair layout,
//              (b) splat scale/zero into fp16x2 (s2, c2) table.
// k-permutation within each aligned 8-group: physical slot p holds logical
// k = (p&1)*4 + (p>>1), i.e. pairs (x0,x4),(x1,x5),(x2,x6),(x3,x7).
// The SAME permutation is produced by the in-gemm W dequant, so MFMA results
// are unchanged (A and B k-slots stay matched).
// ---------------------------------------------------------------------------
__global__ __launch_bounds__(256) void prep_kernel(
    const float* __restrict__ x, _Float16* __restrict__ Xh,
    const float* __restrict__ wscale, const int* __restrict__ wzero,
    uint2* __restrict__ SZ, int nxb) {
  int b = blockIdx.x;
  if (b < nxb) {
    int i = b * 256 + threadIdx.x;           // one 8-float group per thread
    const float4* x4 = (const float4*)x;
    float4 a = x4[2 * i];
    float4 c = x4[2 * i + 1];
    uint4 o;
    o.x = __builtin_bit_cast(unsigned, __builtin_amdgcn_cvt_pkrtz(a.x, c.x));  // (x0, x4)
    o.y = __builtin_bit_cast(unsigned, __builtin_amdgcn_cvt_pkrtz(a.y, c.y));  // (x1, x5)
    o.z = __builtin_bit_cast(unsigned, __builtin_amdgcn_cvt_pkrtz(a.z, c.z));  // (x2, x6)
    o.w = __builtin_bit_cast(unsigned, __builtin_amdgcn_cvt_pkrtz(a.w, c.w));  // (x3, x7)
    ((uint4*)Xh)[i] = o;
  } else {
    int i = (b - nxb) * 256 + threadIdx.x;   // 0 .. OUT_F*NG-1
    float s = wscale[i];
    int zp = wzero[i];
    _Float16 sh = (_Float16)s;
    _Float16 ch = (_Float16)(float)(1032 + zp);  // exact in fp16 (ulp=1 here)
    unsigned s2 = (unsigned)__builtin_bit_cast(unsigned short, sh) * 0x10001u;
    unsigned c2 = (unsigned)__builtin_bit_cast(unsigned short, ch) * 0x10001u;
    SZ[i] = make_uint2(s2, c2);
  }
}

// ---------------------------------------------------------------------------
// Fused W4A16 GEMM.  C[m][n] = sum_k A[m][k] * W[n][k]
// A: M x K fp16 (permuted-k), staged via global_load_lds (no VALU).
// W: packed int4 (8 nibbles / int32), dequantized in-register to fp16 pairs:
//   n = q ^ 8  (so signed q' = n - 8)
//   h = fp16(1024 + n)   via (nib | 0x6400)
//   w = (h - (1032+zp)) * s     -- pk_sub exact, pk_mul fp16
// Tile 128x64, BK=64, 4 waves (each 64x32 -> acc[4][2]), SPLITK=2
// -> grid 64*8*2 = 1024 blocks = 4 blocks/CU, LDS 24 KB/block.
// ---------------------------------------------------------------------------
#define BM 128
#define BN 64
#define BK 64
#define SPLITK 2

__device__ __forceinline__ uint4 dequant8(unsigned v, uint2 szv) {
  unsigned tx = v ^ 0x88888888u;
  half2t s2 = __builtin_bit_cast(half2t, szv.x);
  half2t c2 = __builtin_bit_cast(half2t, szv.y);
  unsigned p0 = (tx & 0x000F000Fu) | 0x64006400u;          // (n0, n4)
  unsigned p1 = ((tx >> 4) & 0x000F000Fu) | 0x64006400u;   // (n1, n5)
  unsigned p2 = ((tx >> 8) & 0x000F000Fu) | 0x64006400u;   // (n2, n6)
  unsigned p3 = ((tx >> 12) & 0x000F000Fu) | 0x64006400u;  // (n3, n7)
  half2t w0 = (__builtin_bit_cast(half2t, p0) - c2) * s2;
  half2t w1 = (__builtin_bit_cast(half2t, p1) - c2) * s2;
  half2t w2 = (__builtin_bit_cast(half2t, p2) - c2) * s2;
  half2t w3 = (__builtin_bit_cast(half2t, p3) - c2) * s2;
  uint4 o;
  o.x = __builtin_bit_cast(unsigned, w0);
  o.y = __builtin_bit_cast(unsigned, w1);
  o.z = __builtin_bit_cast(unsigned, w2);
  o.w = __builtin_bit_cast(unsigned, w3);
  return o;
}

__global__ __launch_bounds__(256, 4) void gemm_fused(
    const _Float16* __restrict__ A, const int* __restrict__ wp,
    const uint2* __restrict__ SZ,
    float* __restrict__ C0, float* __restrict__ C1, int M, int N, int K) {
  __shared__ _Float16 Alds[BM * BK];  // 16 KB
  __shared__ _Float16 Blds[BN * BK];  // 8 KB

  int t = threadIdx.x;
  int wave = t >> 6, lane = t & 63;
  int wm = (wave >> 1) * 64, wn = (wave & 1) * 32;
  int r = lane & 15, quad = lane >> 4;
  int bm = blockIdx.y * BM, bn = blockIdx.x * BN;
  int kz = blockIdx.z * (K / SPLITK);
  int kend = kz + K / SPLITK;

  floatx4 acc[4][2] = {};

  const _Float16* Ag = A + (size_t)bm * K;
  // B staging assignment: int32 index i in tile (0..511): row = i>>3, m = i&7.
  // Thread t handles i = t and i = t+256 -> ds_write addresses i*16 are
  // perfectly linear across the wave (conflict-free b128 writes).
  int rowb = t >> 3, m8 = t & 7;
  const int* wpr0 = wp + (size_t)(bn + rowb) * (IN_F / 8) + m8;
  const int* wpr1 = wp + (size_t)(bn + rowb + 32) * (IN_F / 8) + m8;
  const uint2* sz0 = SZ + (size_t)(bn + rowb) * NG;
  const uint2* sz1 = SZ + (size_t)(bn + rowb + 32) * NG;

  for (int k0 = kz; k0 < kend; k0 += BK) {
    // Issue B-packed + scale loads before the barrier: latency overlaps the
    // tail of the previous iteration's MFMAs.
    unsigned v0 = (unsigned)wpr0[k0 >> 3];
    unsigned v1 = (unsigned)wpr1[k0 >> 3];
    uint2 szv0 = sz0[k0 >> 7];   // BK=64 always lies inside one 128-group
    uint2 szv1 = sz1[k0 >> 7];

    __syncthreads();  // previous compute done before overwriting LDS

    // A: 128x64 fp16 = 1024 x 16B chunks, direct-to-LDS.
#pragma unroll
    for (int j = 0; j < 4; ++j) {
      int c = t + 256 * j;
      int row = c >> 3, kc = c & 7;
      const _Float16* ga = Ag + (size_t)row * K + k0 + kc * 8;
      __builtin_amdgcn_global_load_lds(
          (const __attribute__((address_space(1))) void*)ga,
          (__attribute__((address_space(3))) void*)(&Alds[c * 8]), 16, 0, 0);
    }
    // B: dequant in-register, linear b128 writes.
    ((uint4*)Blds)[t] = dequant8(v0, szv0);
    ((uint4*)Blds)[t + 256] = dequant8(v1, szv1);

    __syncthreads();  // drains vmcnt (A) + lgkmcnt (B)

#pragma unroll
    for (int ks = 0; ks < 2; ++ks) {
      int kk = ks * 32;
      half8 af[4], bf[2];
#pragma unroll
      for (int mi = 0; mi < 4; ++mi)
        af[mi] = *(const half8*)&Alds[(wm + mi * 16 + r) * BK + kk + quad * 8];
#pragma unroll
      for (int ni = 0; ni < 2; ++ni)
        bf[ni] = *(const half8*)&Blds[(wn + ni * 16 + r) * BK + kk + quad * 8];
#pragma unroll
      for (int mi = 0; mi < 4; ++mi)
#pragma unroll
        for (int ni = 0; ni < 2; ++ni)
          acc[mi][ni] = __builtin_amdgcn_mfma_f32_16x16x32_f16(
              af[mi], bf[ni], acc[mi][ni], 0, 0, 0);
    }
  }

  float* C = (blockIdx.z == 0) ? C0 : C1;
  // C/D layout: col = lane&15, row = quad*4 + reg
#pragma unroll
  for (int mi = 0; mi < 4; ++mi) {
#pragma unroll
    for (int ni = 0; ni < 2; ++ni) {
#pragma unroll
      for (int i = 0; i < 4; ++i) {
        int grow = bm + wm + mi * 16 + quad * 4 + i;
        int gcol = bn + wn + ni * 16 + r;
        C[(size_t)grow * N + gcol] = acc[mi][ni][i];
      }
    }
  }
}

__global__ __launch_bounds__(256) void reduce_kernel(
    float* __restrict__ out, const float* __restrict__ part) {
  int i = blockIdx.x * 256 + threadIdx.x;
  float4 a = ((const float4*)out)[i];
  float4 b = ((const float4*)part)[i];
  a.x += b.x; a.y += b.y; a.z += b.z; a.w += b.w;
  ((float4*)out)[i] = a;
}

extern "C" void kernel_launch(void* const* d_in, const int* in_sizes, int n_in,
                              void* d_out, int out_size, void* d_ws, size_t ws_size,
                              hipStream_t stream) {
  const float* x = (const float*)d_in[0];
  const int* wp = (const int*)d_in[1];
  const float* wscale = (const float*)d_in[2];
  const int* wzero = (const int*)d_in[3];
  float* out = (float*)d_out;

  int M = in_sizes[0] / IN_F;  // 1024

  // Workspace: Xh (fp16 M*K = 8.39 MB) | Cpart (f32 M*N = 16.78 MB) | SZ (1 MB)
  _Float16* Xh = (_Float16*)d_ws;
  float* Cpart = (float*)((char*)d_ws + (size_t)M * IN_F * 2);
  uint2* SZ = (uint2*)((char*)d_ws + (size_t)M * IN_F * 2 + (size_t)M * OUT_F * 4);

  int nxb = (M * IN_F / 8) / 256;       // 2048 blocks for x-convert
  int nzb = (OUT_F * NG) / 256;         // 512 blocks for scale/zero table
  prep_kernel<<<nxb + nzb, 256, 0, stream>>>(x, Xh, wscale, wzero, SZ, nxb);

  dim3 grid(OUT_F / BN, M / BM, SPLITK);  // (64, 8, 2) = 1024 blocks
  gemm_fused<<<grid, 256, 0, stream>>>(Xh, wp, SZ, out, Cpart, M, OUT_F, IN_F);

  reduce_kernel<<<(M * OUT_F / 4) / 256, 256, 0, stream>>>(out, Cpart);
}